// Round 1
// baseline (215.489 us; speedup 1.0000x reference)
//
#include <hip/hip_runtime.h>
#include <math.h>

#define EPSF 1e-6f

struct F3   { float x, y, z; };
struct Quat { float x, y, z, w; };
struct Sim3 { F3 t; Quat q; float s; };

__device__ __forceinline__ F3 cross3(F3 a, F3 b) {
    return { a.y*b.z - a.z*b.y, a.z*b.x - a.x*b.z, a.x*b.y - a.y*b.x };
}

__device__ __forceinline__ F3 quat_rotate(Quat q, F3 v) {
    F3 qv { q.x, q.y, q.z };
    F3 uv  = cross3(qv, v);
    F3 cuv = cross3(qv, uv);
    return { v.x + 2.0f*(q.w*uv.x + cuv.x),
             v.y + 2.0f*(q.w*uv.y + cuv.y),
             v.z + 2.0f*(q.w*uv.z + cuv.z) };
}

__device__ __forceinline__ Quat quat_mul(Quat a, Quat b) {
    return {
        a.w*b.x + a.x*b.w + a.y*b.z - a.z*b.y,
        a.w*b.y - a.x*b.z + a.y*b.w + a.z*b.x,
        a.w*b.z + a.x*b.y - a.y*b.x + a.z*b.w,
        a.w*b.w - a.x*b.x - a.y*b.y - a.z*b.z
    };
}

__device__ __forceinline__ Sim3 sim3_inv(Sim3 T) {
    Quat qi { -T.q.x, -T.q.y, -T.q.z, T.q.w };
    float si = 1.0f / T.s;
    F3 r = quat_rotate(qi, T.t);
    return { { -si*r.x, -si*r.y, -si*r.z }, qi, si };
}

__device__ __forceinline__ Sim3 sim3_mul(Sim3 A, Sim3 B) {
    F3 r = quat_rotate(A.q, B.t);
    return { { A.t.x + A.s*r.x, A.t.y + A.s*r.y, A.t.z + A.s*r.z },
             quat_mul(A.q, B.q), A.s * B.s };
}

__device__ __forceinline__ Sim3 load_sim3(const float* __restrict__ p) {
    // rows are 8 floats = 32 B, base is 256-B aligned -> float4-safe
    float4 a = *reinterpret_cast<const float4*>(p);
    float4 b = *reinterpret_cast<const float4*>(p + 4);
    return { {a.x, a.y, a.z}, {a.w, b.x, b.y, b.z}, b.w };
}

// out[0..2]=tau, out[3..5]=phi, out[6]=sigma — mirrors the jax reference
// branch-for-branch (same where() structure, same f32 W; solve done in
// double via Cramer, which matches the reference's f32 LU well within the
// 4.88 absmax threshold).
__device__ __forceinline__ void sim3_log(Sim3 T, float out[7]) {
    float qx = T.q.x, qy = T.q.y, qz = T.q.z, qw = T.q.w;
    float nv = sqrtf(qx*qx + qy*qy + qz*qz);
    float theta_r = 2.0f * atan2f(nv, qw);
    float fac = (nv < EPSF) ? 2.0f : (theta_r / nv);
    float px = fac*qx, py = fac*qy, pz = fac*qz;
    float sigma = logf(T.s);
    float theta = sqrtf(px*px + py*py + pz*pz);

    bool sig_small = fabsf(sigma) < EPSF;
    bool th_small  = theta < EPSF;
    float sg = sig_small ? 1.0f : sigma;
    float th = th_small  ? 1.0f : theta;
    float scale = expf(sigma);
    float th2 = th*th, sg2 = sg*sg;
    float C = sig_small ? 1.0f : (scale - 1.0f) / sg;
    float sth = sinf(th), cth = cosf(th);
    float A_ss = th_small ? 0.5f : (1.0f - cth) / th2;
    float B_ss = th_small ? (1.0f/6.0f) : (th - sth) / (th2 * th);
    float a = scale * sth;
    float b = scale * cth;
    float c = th2 + sg2;
    float A_g = (a*sg + (1.0f - b)*th) / (th * c);
    float B_g = (C - ((b - 1.0f)*sg + a*th) / c) / th2;
    float A_ts = ((sg - 1.0f)*scale + 1.0f) / sg2;
    float B_ts = (scale*(sg2 - 2.0f*sg + 2.0f) - 2.0f) / (2.0f*sg2*sg);
    float A = sig_small ? A_ss : (th_small ? A_ts : A_g);
    float B = sig_small ? B_ss : (th_small ? B_ts : B_g);

    // Phi = skew(phi); Q = Phi @ Phi (explicit, matching reference order)
    float P01 = -pz, P02 =  py;
    float P10 =  pz, P12 = -px;
    float P20 = -py, P21 =  px;
    float Q00 = P01*P10 + P02*P20;
    float Q01 = P02*P21;
    float Q02 = P01*P12;
    float Q10 = P12*P20;
    float Q11 = P10*P01 + P12*P21;
    float Q12 = P10*P02;
    float Q20 = P21*P10;
    float Q21 = P20*P01;
    float Q22 = P20*P02 + P21*P12;

    float W00 = C + B*Q00,          W01 = A*P01 + B*Q01, W02 = A*P02 + B*Q02;
    float W10 = A*P10 + B*Q10,      W11 = C + B*Q11,     W12 = A*P12 + B*Q12;
    float W20 = A*P20 + B*Q20,      W21 = A*P21 + B*Q21, W22 = C + B*Q22;

    // tau = W^{-1} t  (Cramer/adjugate in double)
    double d00=W00, d01=W01, d02=W02, d10=W10, d11=W11, d12=W12, d20=W20, d21=W21, d22=W22;
    double c00 = d11*d22 - d12*d21;
    double c01 = d12*d20 - d10*d22;
    double c02 = d10*d21 - d11*d20;
    double det = d00*c00 + d01*c01 + d02*c02;
    double idet = 1.0 / det;
    double tx = T.t.x, ty = T.t.y, tz = T.t.z;
    out[0] = (float)((c00*tx + (d02*d21 - d01*d22)*ty + (d01*d12 - d02*d11)*tz) * idet);
    out[1] = (float)((c01*tx + (d00*d22 - d02*d20)*ty + (d02*d10 - d00*d12)*tz) * idet);
    out[2] = (float)((c02*tx + (d01*d20 - d00*d21)*ty + (d00*d11 - d01*d10)*tz) * idet);
    out[3] = px; out[4] = py; out[5] = pz; out[6] = sigma;
}

__global__ void __launch_bounds__(256) pgo_kernel(
        const float* __restrict__ Twc,
        const float* __restrict__ Tp_inv,
        const float* __restrict__ To_inv,
        const float* __restrict__ pw,
        const float* __restrict__ ow,
        const int*   __restrict__ edges,
        const float* __restrict__ T_lc,
        float*       __restrict__ out,
        int n) {
    int i = blockIdx.x * blockDim.x + threadIdx.x;
    if (i >= n) return;
    size_t i8 = (size_t)i * 8;
    size_t i7 = (size_t)i * 7;

    Sim3 Ti = load_sim3(Twc + i8);
    Sim3 Tj = load_sim3(Twc + i8 + 8);
    Sim3 delta = sim3_mul(sim3_inv(Ti), Tj);

    float rp[7], ro[7], rl[7];
    sim3_log(sim3_mul(delta, load_sim3(Tp_inv + i8)), rp);
    sim3_log(sim3_mul(delta, load_sim3(To_inv + i8)), ro);

    int e0 = edges[2*(size_t)i];
    int e1 = edges[2*(size_t)i + 1];
    Sim3 dlc = sim3_mul(sim3_inv(load_sim3(Twc + (size_t)e0 * 8)),
                        load_sim3(Twc + (size_t)e1 * 8));
    sim3_log(sim3_mul(dlc, load_sim3(T_lc + i8)), rl);

    #pragma unroll
    for (int k = 0; k < 7; ++k) {
        out[i7 + k] = rp[k]*pw[i7 + k] + ro[k]*ow[i7 + k] + rl[k];
    }
}

extern "C" void kernel_launch(void* const* d_in, const int* in_sizes, int n_in,
                              void* d_out, int out_size, void* d_ws, size_t ws_size,
                              hipStream_t stream) {
    const float* Twc   = (const float*)d_in[0];
    const float* Tp    = (const float*)d_in[1];
    const float* To    = (const float*)d_in[2];
    const float* pw    = (const float*)d_in[3];
    const float* ow    = (const float*)d_in[4];
    const int*   edges = (const int*)d_in[5];
    const float* Tlc   = (const float*)d_in[6];
    float* out = (float*)d_out;

    int n = in_sizes[1] / 8;  // N_FRAME - 1
    const int block = 256;
    int grid = (n + block - 1) / block;
    pgo_kernel<<<grid, block, 0, stream>>>(Twc, Tp, To, pw, ow, edges, Tlc, out, n);
}